// Round 10
// baseline (1297.153 us; speedup 1.0000x reference)
//
#include <hip/hip_runtime.h>
#include <math.h>

// Problem constants (fixed by reference setup_inputs)
#define NN  50000
#define EE  400000
#define DD  64
#define HH  4
#define HC  256      // H * C
#define EDD 16

__device__ __forceinline__ float gelu_exact(float x) {
    return 0.5f * x * (1.0f + erff(x * 0.70710678118654752440f));
}
// fast exp via v_exp_f32: exp(x)=2^(x*log2e). exp2(-inf)=0 preserved.
__device__ __forceinline__ float fast_exp(float x) {
    return __builtin_amdgcn_exp2f(x * 1.44269504088896340736f);
}

// ---------- fills ----------
__global__ void fill_u32(unsigned* __restrict__ p, unsigned v, int n) {
    int i = blockIdx.x * blockDim.x + threadIdx.x;
    int s = gridDim.x * blockDim.x;
    for (; i < n; i += s) p[i] = v;
}

// ---------- CSR build ----------
__global__ void hist_k(const int* __restrict__ ei, int* __restrict__ deg) {
    int e = blockIdx.x * 256 + threadIdx.x;
    if (e < EE) atomicAdd(&deg[ei[EE + e]], 1);
}
__global__ void scan1_k(const int* __restrict__ deg, int* __restrict__ rowptr,
                        int* __restrict__ bsum) {
    __shared__ int s[256];
    int t = threadIdx.x, i = blockIdx.x * 256 + t;
    int v = (i < NN) ? deg[i] : 0;
    s[t] = v; __syncthreads();
    for (int o = 1; o < 256; o <<= 1) {
        int u = (t >= o) ? s[t - o] : 0;
        __syncthreads();
        s[t] += u;
        __syncthreads();
    }
    if (i < NN) rowptr[i] = s[t] - v;
    if (t == 255) bsum[blockIdx.x] = s[255];
}
__global__ void scan2_k(int* __restrict__ bsum, int nb) {
    __shared__ int s[256];
    int t = threadIdx.x;
    int v = (t < nb) ? bsum[t] : 0;
    s[t] = v; __syncthreads();
    for (int o = 1; o < 256; o <<= 1) {
        int u = (t >= o) ? s[t - o] : 0;
        __syncthreads();
        s[t] += u;
        __syncthreads();
    }
    if (t < nb) bsum[t] = s[t] - v;
}
__global__ void scan3_k(int* __restrict__ rowptr, const int* __restrict__ bsum,
                        int* __restrict__ cursor) {
    int i = blockIdx.x * 256 + threadIdx.x;
    if (i < NN) {
        int r = rowptr[i] + bsum[blockIdx.x];
        rowptr[i] = r;
        cursor[i] = r;
    }
    if (i == 0) rowptr[NN] = EE;
}
// scatter srcs, (src,dst) pairs AND edge_attr into CSR order
__global__ void scatter_k(const int* __restrict__ ei, int* __restrict__ cursor,
                          const float* __restrict__ ea,
                          int* __restrict__ srcs, int2* __restrict__ sd,
                          float* __restrict__ ea_s) {
    int e = blockIdx.x * 256 + threadIdx.x;
    if (e >= EE) return;
    int src = ei[e];
    int dst = ei[EE + e];
    int pos = atomicAdd(&cursor[dst], 1);
    srcs[pos] = src;
    sd[pos] = make_int2(src, dst);
    const float4* s4 = (const float4*)(ea + (long)e * EDD);
    float4* d4 = (float4*)(ea_s + (long)pos * EDD);
    d4[0] = s4[0]; d4[1] = s4[1]; d4[2] = s4[2]; d4[3] = s4[3];
}

// ---------- node GEMM: Y[N,256] = X[N,64] @ W[64,256] + b ----------
__global__ __launch_bounds__(256) void gemm_node(
    const float* __restrict__ X, const float* __restrict__ W,
    const float* __restrict__ b, float* __restrict__ Y)
{
    const int col  = threadIdx.x;
    const int base = blockIdx.x * 32;

    float wk[64];
#pragma unroll
    for (int k = 0; k < 64; k++) wk[k] = W[k * 256 + col];
    const float bb = b[col];

#pragma unroll 2
    for (int r = 0; r < 32; r++) {
        const int row = base + r;
        const int rr  = (row < NN) ? row : (NN - 1);
        const float* __restrict__ xrow = X + (long)rr * 64;
        float a0 = 0.f, a1 = 0.f, a2 = 0.f, a3 = 0.f;
#pragma unroll
        for (int k = 0; k < 64; k += 4) {
            a0 = fmaf(xrow[k],     wk[k],     a0);
            a1 = fmaf(xrow[k + 1], wk[k + 1], a1);
            a2 = fmaf(xrow[k + 2], wk[k + 2], a2);
            a3 = fmaf(xrow[k + 3], wk[k + 3], a3);
        }
        if (row < NN) Y[(long)row * 256 + col] = (a0 + a1) + (a2 + a3) + bb;
    }
}

// ---------- phase A: edge logits (edge-parallel, depth-2 pipelined) ----------
// Lane layout: head h = lane>>4, channel quad (lane&15)*4.
__global__ __launch_bounds__(256, 4) void edge_logit_k(
    const int2* __restrict__ sd,
    const float* __restrict__ ea_s,
    const float* __restrict__ We, const float* __restrict__ att,
    const float* __restrict__ xl, const float* __restrict__ xr,
    float* __restrict__ alpha4)
{
    const int lane = threadIdx.x & 63;
    const int gc   = ((lane >> 4) << 6) + ((lane & 15) << 2);

    float wreg[EDD][4];
#pragma unroll
    for (int k = 0; k < EDD; k++) {
        const float4 w4 = *(const float4*)(We + k * HC + gc);
        wreg[k][0] = w4.x; wreg[k][1] = w4.y; wreg[k][2] = w4.z; wreg[k][3] = w4.w;
    }
#pragma unroll
    for (int k = 0; k < EDD; k++)
#pragma unroll
        for (int j = 0; j < 4; j++) asm volatile("" : "+v"(wreg[k][j]));

    const float4 a4 = *(const float4*)(att + gc);

    const int wid = blockIdx.x * 4 + (threadIdx.x >> 6);
    const int nw  = gridDim.x * 4;
    const int cpw = (EE + nw - 1) / nw;
    const int pbeg = wid * cpw;
    const int pend = (pbeg + cpw < EE) ? (pbeg + cpw) : EE;
    if (pbeg >= pend) return;

    float4 xlA, xrA, xlB, xrB;
    float  eaA[EDD], eaB[EDD];    // wave-uniform -> SGPRs

#define LOADP(P, XL, XR, EA)                                                   \
    {                                                                          \
        const int2 _sd = sd[P];                                                \
        const int _s = __builtin_amdgcn_readfirstlane(_sd.x);                  \
        const int _d = __builtin_amdgcn_readfirstlane(_sd.y);                  \
        const float* __restrict__ _eap = ea_s + (long)(P) * EDD;               \
        _Pragma("unroll")                                                      \
        for (int k = 0; k < EDD; k++) EA[k] = _eap[k];                         \
        XL = *(const float4*)(xl + (long)_s * HC + gc);                        \
        XR = *(const float4*)(xr + (long)_d * HC + gc);                        \
    }

#define COMPP(P, XL, XR, EA)                                                   \
    {                                                                          \
        float ez0 = 0.f, ez1 = 0.f, ez2 = 0.f, ez3 = 0.f;                      \
        _Pragma("unroll")                                                      \
        for (int k = 0; k < EDD; k++) {                                        \
            ez0 = fmaf(EA[k], wreg[k][0], ez0);                                \
            ez1 = fmaf(EA[k], wreg[k][1], ez1);                                \
            ez2 = fmaf(EA[k], wreg[k][2], ez2);                                \
            ez3 = fmaf(EA[k], wreg[k][3], ez3);                                \
        }                                                                      \
        float s0 = XL.x + XR.x + ez0;                                          \
        float s1 = XL.y + XR.y + ez1;                                          \
        float s2 = XL.z + XR.z + ez2;                                          \
        float s3 = XL.w + XR.w + ez3;                                          \
        s0 = (s0 > 0.f) ? s0 : 0.2f * s0;                                      \
        s1 = (s1 > 0.f) ? s1 : 0.2f * s1;                                      \
        s2 = (s2 > 0.f) ? s2 : 0.2f * s2;                                      \
        s3 = (s3 > 0.f) ? s3 : 0.2f * s3;                                      \
        float part = fmaf(s0, a4.x, fmaf(s1, a4.y, fmaf(s2, a4.z, s3 * a4.w)));\
        part += __shfl_xor(part, 1, 64);                                       \
        part += __shfl_xor(part, 2, 64);                                       \
        part += __shfl_xor(part, 4, 64);                                       \
        part += __shfl_xor(part, 8, 64);                                       \
        const float h0 = __shfl(part, 0, 64);                                  \
        const float h1 = __shfl(part, 16, 64);                                 \
        const float h2 = __shfl(part, 32, 64);                                 \
        const float h3 = __shfl(part, 48, 64);                                 \
        if (lane == 0) {                                                       \
            float4 o; o.x = h0; o.y = h1; o.z = h2; o.w = h3;                  \
            *(float4*)(alpha4 + (long)(P) * 4) = o;                            \
        }                                                                      \
    }

    int p = pbeg;
    LOADP(p, xlA, xrA, eaA);
    while (p < pend) {
        if (p + 1 < pend) LOADP(p + 1, xlB, xrB, eaB);
        COMPP(p, xlA, xrA, eaA);
        p++;
        if (p >= pend) break;
        if (p + 1 < pend) LOADP(p + 1, xlA, xrA, eaA);
        COMPP(p, xlB, xrB, eaB);
        p++;
    }
#undef LOADP
#undef COMPP
}

// ---------- phase B: per-node softmax + aggregation + LN/GELU ----------
// Lane = (head h = lane>>4, edge-slot jj = lane&15). Full 16-edge batches are
// compile-time unrolled so the 16 gathers pipeline; masked tail handles rest.
__global__ __launch_bounds__(256, 4) void node_agg_k(
    const int* __restrict__ rowptr, const int* __restrict__ srcs,
    const float* __restrict__ alpha4, const float* __restrict__ xl,
    const float* __restrict__ bias, const float* __restrict__ lng,
    const float* __restrict__ lnb, const float* __restrict__ identity,
    float* __restrict__ x1out, float* __restrict__ outp, int mode)
{
    const int lane = threadIdx.x & 63;
    const int n    = blockIdx.x * 4 + (threadIdx.x >> 6);   // 12500*4 = 50000
    const int h    = lane >> 4;
    const int jj   = lane & 15;
    const int gc   = (h << 6) + (jj << 2);
    const int cb   = jj << 2;

    const int p0 = __builtin_amdgcn_readfirstlane(rowptr[n]);
    const int p1 = __builtin_amdgcn_readfirstlane(rowptr[n + 1]);
    const int deg  = p1 - p0;
    const int nfull = deg >> 4;           // full 16-edge batches
    const int ptail = p0 + (nfull << 4);

    // pass 1: per-head max
    float mh = -INFINITY;
    {
        int b = p0;
        for (int f = 0; f < nfull; f++, b += 16)
            mh = fmaxf(mh, alpha4[(long)(b + jj) * 4 + h]);
        if (ptail < p1) {
            const int p = ptail + jj;
            if (p < p1) mh = fmaxf(mh, alpha4[(long)p * 4 + h]);
        }
    }
    mh = fmaxf(mh, __shfl_xor(mh, 1, 64));
    mh = fmaxf(mh, __shfl_xor(mh, 2, 64));
    mh = fmaxf(mh, __shfl_xor(mh, 4, 64));
    mh = fmaxf(mh, __shfl_xor(mh, 8, 64));

    // pass 2: weights + denom + gather-aggregate
    float dsum = 0.f;
    float ac0 = 0.f, ac1 = 0.f, ac2 = 0.f, ac3 = 0.f;
    {
        int b = p0;
        for (int f = 0; f < nfull; f++, b += 16) {
            const float a = alpha4[(long)(b + jj) * 4 + h];
            const float w = fast_exp(a - mh);
            dsum += w;
            const int sv = srcs[b + jj];
#pragma unroll
            for (int j = 0; j < 16; j++) {
                const int sj   = __shfl(sv, j, 64);
                const float wj = __shfl(w, (lane & 48) | j, 64);
                const float4 x4 = *(const float4*)(xl + (long)sj * HC + gc);
                ac0 = fmaf(wj, x4.x, ac0);
                ac1 = fmaf(wj, x4.y, ac1);
                ac2 = fmaf(wj, x4.z, ac2);
                ac3 = fmaf(wj, x4.w, ac3);
            }
        }
        if (ptail < p1) {
            const int p = ptail + jj;
            const bool v = (p < p1);
            const int pa = v ? p : (p1 - 1);
            float a = alpha4[(long)pa * 4 + h];
            if (!v) a = -INFINITY;
            const float w = fast_exp(a - mh);      // 0 for invalid lanes
            dsum += w;
            const int sv = srcs[pa];
            const int cnt = p1 - ptail;
            for (int j = 0; j < cnt; j++) {
                const int sj   = __shfl(sv, j, 64);
                const float wj = __shfl(w, (lane & 48) | j, 64);
                const float4 x4 = *(const float4*)(xl + (long)sj * HC + gc);
                ac0 = fmaf(wj, x4.x, ac0);
                ac1 = fmaf(wj, x4.y, ac1);
                ac2 = fmaf(wj, x4.z, ac2);
                ac3 = fmaf(wj, x4.w, ac3);
            }
        }
    }
    dsum += __shfl_xor(dsum, 1, 64);
    dsum += __shfl_xor(dsum, 2, 64);
    dsum += __shfl_xor(dsum, 4, 64);
    dsum += __shfl_xor(dsum, 8, 64);

    const float inv = 1.0f / (dsum + 1e-16f);
    float v0 = ac0 * inv, v1 = ac1 * inv, v2 = ac2 * inv, v3 = ac3 * inv;

    // head mean across the 4 groups
    v0 += __shfl_xor(v0, 16, 64); v0 += __shfl_xor(v0, 32, 64);
    v1 += __shfl_xor(v1, 16, 64); v1 += __shfl_xor(v1, 32, 64);
    v2 += __shfl_xor(v2, 16, 64); v2 += __shfl_xor(v2, 32, 64);
    v3 += __shfl_xor(v3, 16, 64); v3 += __shfl_xor(v3, 32, 64);

    if (lane < 16) {   // group 0 finishes LN + GELU + store
        const float4 b4 = *(const float4*)(bias + cb);
        v0 = v0 * 0.25f + b4.x;
        v1 = v1 * 0.25f + b4.y;
        v2 = v2 * 0.25f + b4.z;
        v3 = v3 * 0.25f + b4.w;

        float s = (v0 + v1) + (v2 + v3);
        s += __shfl_xor(s, 1, 64); s += __shfl_xor(s, 2, 64);
        s += __shfl_xor(s, 4, 64); s += __shfl_xor(s, 8, 64);
        const float mu = s * (1.0f / 64.0f);
        const float d0 = v0 - mu, d1 = v1 - mu, d2 = v2 - mu, d3 = v3 - mu;
        float q = (d0 * d0 + d1 * d1) + (d2 * d2 + d3 * d3);
        q += __shfl_xor(q, 1, 64); q += __shfl_xor(q, 2, 64);
        q += __shfl_xor(q, 4, 64); q += __shfl_xor(q, 8, 64);
        const float rs = rsqrtf(q * (1.0f / 64.0f) + 1e-5f);

        const float4 g4 = *(const float4*)(lng + cb);
        const float4 c4 = *(const float4*)(lnb + cb);
        float y0 = d0 * rs * g4.x + c4.x;
        float y1 = d1 * rs * g4.y + c4.y;
        float y2 = d2 * rs * g4.z + c4.z;
        float y3 = d3 * rs * g4.w + c4.w;

        if (mode == 0) {
            float4 o;
            o.x = gelu_exact(y0); o.y = gelu_exact(y1);
            o.z = gelu_exact(y2); o.w = gelu_exact(y3);
            *(float4*)(x1out + (long)n * DD + cb) = o;
        } else {
            const float4 id = *(const float4*)(identity + (long)n * DD + cb);
            float4 o;
            o.x = gelu_exact(y0 + id.x); o.y = gelu_exact(y1 + id.y);
            o.z = gelu_exact(y2 + id.z); o.w = gelu_exact(y3 + id.w);
            *(float4*)(outp + (long)n * DD + cb) = o;
        }
    }
}

// ---------- launch ----------
extern "C" void kernel_launch(void* const* d_in, const int* in_sizes, int n_in,
                              void* d_out, int out_size, void* d_ws, size_t ws_size,
                              hipStream_t stream) {
    (void)in_sizes; (void)n_in; (void)out_size; (void)ws_size;

    const float* h     = (const float*)d_in[0];
    const int*   ei    = (const int*)d_in[1];
    const float* ea    = (const float*)d_in[2];
    const float* g1Wl  = (const float*)d_in[3];
    const float* g1bl  = (const float*)d_in[4];
    const float* g1Wr  = (const float*)d_in[5];
    const float* g1br  = (const float*)d_in[6];
    const float* g1We  = (const float*)d_in[7];
    const float* g1att = (const float*)d_in[8];
    const float* g1bias= (const float*)d_in[9];
    const float* ln1g  = (const float*)d_in[10];
    const float* ln1b  = (const float*)d_in[11];
    const float* g2Wl  = (const float*)d_in[12];
    const float* g2bl  = (const float*)d_in[13];
    const float* g2Wr  = (const float*)d_in[14];
    const float* g2br  = (const float*)d_in[15];
    const float* g2We  = (const float*)d_in[16];
    const float* g2att = (const float*)d_in[17];
    const float* g2bias= (const float*)d_in[18];
    const float* ln2g  = (const float*)d_in[19];
    const float* ln2b  = (const float*)d_in[20];

    float* out = (float*)d_out;

    // workspace layout (4-byte units)
    float* ws = (float*)d_ws;
    size_t o = 0;
    float* xl     = ws + o;          o += 12800000;   // N*256
    float* xr     = ws + o;          o += 12800000;   // N*256
    float* x1     = ws + o;          o += 3200000;    // N*64
    int*   rowptr = (int*)(ws + o);  o += 50004;      // N+1
    int*   deg    = (int*)(ws + o);  o += 50000;
    int*   cursor = (int*)(ws + o);  o += 50000;
    int*   bsum   = (int*)(ws + o);  o += 256;
    int*   srcs   = (int*)(ws + o);  o += 400000;
    int2*  sd     = (int2*)(ws + o); o += 800000;     // (src,dst) pairs
    float* ea_s   = ws + o;          o += 6400000;    // E*16, CSR-sorted
    float* alpha4 = ws + o;          o += 1600000;    // E*4 logits

    const int GEMM_BLOCKS  = (NN + 31) / 32;    // 1563
    const int SCAN_BLOCKS  = (NN + 255) / 256;  // 196
    const int EDGE_BLOCKS  = (EE + 255) / 256;  // 1563
    const int LOGIT_BLOCKS = 2048;              // 8192 waves, ~49 edges each
    const int NODE_BLOCKS  = (NN + 3) / 4;      // 12500

    // ----- CSR build (once; graph identical for both layers) -----
    fill_u32<<<256, 256, 0, stream>>>((unsigned*)deg, 0u, NN);
    hist_k<<<EDGE_BLOCKS, 256, 0, stream>>>(ei, deg);
    scan1_k<<<SCAN_BLOCKS, 256, 0, stream>>>(deg, rowptr, bsum);
    scan2_k<<<1, 256, 0, stream>>>(bsum, SCAN_BLOCKS);
    scan3_k<<<SCAN_BLOCKS, 256, 0, stream>>>(rowptr, bsum, cursor);
    scatter_k<<<EDGE_BLOCKS, 256, 0, stream>>>(ei, cursor, ea, srcs, sd, ea_s);

    // ----- layer 1 -----
    gemm_node<<<GEMM_BLOCKS, 256, 0, stream>>>(h, g1Wl, g1bl, xl);
    gemm_node<<<GEMM_BLOCKS, 256, 0, stream>>>(h, g1Wr, g1br, xr);
    edge_logit_k<<<LOGIT_BLOCKS, 256, 0, stream>>>(sd, ea_s, g1We, g1att,
                                                   xl, xr, alpha4);
    node_agg_k<<<NODE_BLOCKS, 256, 0, stream>>>(rowptr, srcs, alpha4, xl,
                                                g1bias, ln1g, ln1b, h, x1, out, 0);

    // ----- layer 2 -----
    gemm_node<<<GEMM_BLOCKS, 256, 0, stream>>>(x1, g2Wl, g2bl, xl);
    gemm_node<<<GEMM_BLOCKS, 256, 0, stream>>>(x1, g2Wr, g2br, xr);
    edge_logit_k<<<LOGIT_BLOCKS, 256, 0, stream>>>(sd, ea_s, g2We, g2att,
                                                   xl, xr, alpha4);
    node_agg_k<<<NODE_BLOCKS, 256, 0, stream>>>(rowptr, srcs, alpha4, xl,
                                                g2bias, ln2g, ln2b, h, x1, out, 1);
}

// Round 11
// 661.191 us; speedup vs baseline: 1.9618x; 1.9618x over previous
//
#include <hip/hip_runtime.h>
#include <math.h>

// Problem constants (fixed by reference setup_inputs)
#define NN  50000
#define EE  400000
#define DD  64
#define HH  4
#define HC  256      // H * C
#define EDD 16

__device__ __forceinline__ float gelu_exact(float x) {
    return 0.5f * x * (1.0f + erff(x * 0.70710678118654752440f));
}
// fast exp via v_exp_f32: exp(x)=2^(x*log2e). exp2(-inf)=0 preserved.
__device__ __forceinline__ float fast_exp(float x) {
    return __builtin_amdgcn_exp2f(x * 1.44269504088896340736f);
}

// ---------- fills ----------
__global__ void fill_u32(unsigned* __restrict__ p, unsigned v, int n) {
    int i = blockIdx.x * blockDim.x + threadIdx.x;
    int s = gridDim.x * blockDim.x;
    for (; i < n; i += s) p[i] = v;
}

// ---------- CSR build ----------
__global__ void hist_k(const int* __restrict__ ei, int* __restrict__ deg) {
    int e = blockIdx.x * 256 + threadIdx.x;
    if (e < EE) atomicAdd(&deg[ei[EE + e]], 1);
}
__global__ void scan1_k(const int* __restrict__ deg, int* __restrict__ rowptr,
                        int* __restrict__ bsum) {
    __shared__ int s[256];
    int t = threadIdx.x, i = blockIdx.x * 256 + t;
    int v = (i < NN) ? deg[i] : 0;
    s[t] = v; __syncthreads();
    for (int o = 1; o < 256; o <<= 1) {
        int u = (t >= o) ? s[t - o] : 0;
        __syncthreads();
        s[t] += u;
        __syncthreads();
    }
    if (i < NN) rowptr[i] = s[t] - v;
    if (t == 255) bsum[blockIdx.x] = s[255];
}
__global__ void scan2_k(int* __restrict__ bsum, int nb) {
    __shared__ int s[256];
    int t = threadIdx.x;
    int v = (t < nb) ? bsum[t] : 0;
    s[t] = v; __syncthreads();
    for (int o = 1; o < 256; o <<= 1) {
        int u = (t >= o) ? s[t - o] : 0;
        __syncthreads();
        s[t] += u;
        __syncthreads();
    }
    if (t < nb) bsum[t] = s[t] - v;
}
__global__ void scan3_k(int* __restrict__ rowptr, const int* __restrict__ bsum,
                        int* __restrict__ cursor) {
    int i = blockIdx.x * 256 + threadIdx.x;
    if (i < NN) {
        int r = rowptr[i] + bsum[blockIdx.x];
        rowptr[i] = r;
        cursor[i] = r;
    }
    if (i == 0) rowptr[NN] = EE;
}
// scatter srcs, dsts AND edge_attr into CSR order
__global__ void scatter_k(const int* __restrict__ ei, int* __restrict__ cursor,
                          const float* __restrict__ ea,
                          int* __restrict__ srcs, int* __restrict__ dsts,
                          float* __restrict__ ea_s) {
    int e = blockIdx.x * 256 + threadIdx.x;
    if (e >= EE) return;
    int dst = ei[EE + e];
    int pos = atomicAdd(&cursor[dst], 1);
    srcs[pos] = ei[e];
    dsts[pos] = dst;
    const float4* s4 = (const float4*)(ea + (long)e * EDD);
    float4* d4 = (float4*)(ea_s + (long)pos * EDD);
    d4[0] = s4[0]; d4[1] = s4[1]; d4[2] = s4[2]; d4[3] = s4[3];
}

// ---------- node GEMM (dual): Y{l,r}[N,256] = X[N,64] @ W{l,r}[64,256] + b{l,r} ----------
// blockIdx.y selects the (W,b,Y) set; halves dispatch count vs two launches.
__global__ __launch_bounds__(256) void gemm_node2(
    const float* __restrict__ X,
    const float* __restrict__ Wl, const float* __restrict__ bl,
    const float* __restrict__ Wr, const float* __restrict__ br,
    float* __restrict__ Yl, float* __restrict__ Yr)
{
    const int col  = threadIdx.x;
    const int base = blockIdx.x * 32;
    const float* __restrict__ W = blockIdx.y ? Wr : Wl;
    const float* __restrict__ b = blockIdx.y ? br : bl;
    float* __restrict__ Y       = blockIdx.y ? Yr : Yl;

    float wk[64];
#pragma unroll
    for (int k = 0; k < 64; k++) wk[k] = W[k * 256 + col];
    const float bb = b[col];

#pragma unroll 2
    for (int r = 0; r < 32; r++) {
        const int row = base + r;
        const int rr  = (row < NN) ? row : (NN - 1);
        const float* __restrict__ xrow = X + (long)rr * 64;
        float a0 = 0.f, a1 = 0.f, a2 = 0.f, a3 = 0.f;
#pragma unroll
        for (int k = 0; k < 64; k += 4) {
            a0 = fmaf(xrow[k],     wk[k],     a0);
            a1 = fmaf(xrow[k + 1], wk[k + 1], a1);
            a2 = fmaf(xrow[k + 2], wk[k + 2], a2);
            a3 = fmaf(xrow[k + 3], wk[k + 3], a3);
        }
        if (row < NN) Y[(long)row * 256 + col] = (a0 + a1) + (a2 + a3) + bb;
    }
}

// ---------- phase A: edge logits (edge-parallel, no pipeline — R8 proven) ----------
// Lane layout: head h = lane>>4, channel quad (lane&15)*4. One wave per
// contiguous edge slice; iterations independent -> latency hidden by waves.
// NOTE: do NOT add manual A/B pipelining here — wreg(64) + pipeline state
// exceeds the VGPR budget and spills (R9: WRITE_SIZE 9->259 MB, 116->420 us).
__global__ __launch_bounds__(256, 4) void edge_logit_k(
    const int* __restrict__ srcs, const int* __restrict__ dsts,
    const float* __restrict__ ea_s,
    const float* __restrict__ We, const float* __restrict__ att,
    const float* __restrict__ xl, const float* __restrict__ xr,
    float* __restrict__ alpha4)
{
    const int lane = threadIdx.x & 63;
    const int gc   = ((lane >> 4) << 6) + ((lane & 15) << 2);

    float wreg[EDD][4];
#pragma unroll
    for (int k = 0; k < EDD; k++) {
        const float4 w4 = *(const float4*)(We + k * HC + gc);
        wreg[k][0] = w4.x; wreg[k][1] = w4.y; wreg[k][2] = w4.z; wreg[k][3] = w4.w;
    }
#pragma unroll
    for (int k = 0; k < EDD; k++)
#pragma unroll
        for (int j = 0; j < 4; j++) asm volatile("" : "+v"(wreg[k][j]));

    const float4 a4 = *(const float4*)(att + gc);

    const int wid = blockIdx.x * 4 + (threadIdx.x >> 6);
    const int nw  = gridDim.x * 4;
    const int cpw = (EE + nw - 1) / nw;
    const int pbeg = wid * cpw;
    const int pend = (pbeg + cpw < EE) ? (pbeg + cpw) : EE;

    for (int p = pbeg; p < pend; p++) {
        const int src = __builtin_amdgcn_readfirstlane(srcs[p]);
        const int dst = __builtin_amdgcn_readfirstlane(dsts[p]);
        float eav[EDD];
        const float* __restrict__ eap = ea_s + (long)p * EDD;
#pragma unroll
        for (int k = 0; k < EDD; k++) eav[k] = eap[k];

        const float4 xlv = *(const float4*)(xl + (long)src * HC + gc);
        const float4 xrv = *(const float4*)(xr + (long)dst * HC + gc);

        float ez0 = 0.f, ez1 = 0.f, ez2 = 0.f, ez3 = 0.f;
#pragma unroll
        for (int k = 0; k < EDD; k++) {
            ez0 = fmaf(eav[k], wreg[k][0], ez0);
            ez1 = fmaf(eav[k], wreg[k][1], ez1);
            ez2 = fmaf(eav[k], wreg[k][2], ez2);
            ez3 = fmaf(eav[k], wreg[k][3], ez3);
        }
        float s0 = xlv.x + xrv.x + ez0;
        float s1 = xlv.y + xrv.y + ez1;
        float s2 = xlv.z + xrv.z + ez2;
        float s3 = xlv.w + xrv.w + ez3;
        s0 = (s0 > 0.f) ? s0 : 0.2f * s0;
        s1 = (s1 > 0.f) ? s1 : 0.2f * s1;
        s2 = (s2 > 0.f) ? s2 : 0.2f * s2;
        s3 = (s3 > 0.f) ? s3 : 0.2f * s3;
        float part = fmaf(s0, a4.x, fmaf(s1, a4.y, fmaf(s2, a4.z, s3 * a4.w)));
        part += __shfl_xor(part, 1, 64);
        part += __shfl_xor(part, 2, 64);
        part += __shfl_xor(part, 4, 64);
        part += __shfl_xor(part, 8, 64);

        const float h0 = __shfl(part, 0, 64);
        const float h1 = __shfl(part, 16, 64);
        const float h2 = __shfl(part, 32, 64);
        const float h3 = __shfl(part, 48, 64);
        if (lane == 0) {
            float4 o; o.x = h0; o.y = h1; o.z = h2; o.w = h3;
            *(float4*)(alpha4 + (long)p * 4) = o;
        }
    }
}

// ---------- phase B: per-node softmax + aggregation + LN/GELU (R8 proven) ----------
__global__ __launch_bounds__(256) void node_agg_k(
    const int* __restrict__ rowptr, const int* __restrict__ srcs,
    const float* __restrict__ alpha4, const float* __restrict__ xl,
    const float* __restrict__ bias, const float* __restrict__ lng,
    const float* __restrict__ lnb, const float* __restrict__ identity,
    float* __restrict__ x1out, float* __restrict__ outp, int mode)
{
    const int lane = threadIdx.x & 63;
    const int n    = blockIdx.x * 4 + (threadIdx.x >> 6);   // 12500*4 = 50000
    const int h    = lane >> 4;
    const int jj   = lane & 15;
    const int gc   = (h << 6) + (jj << 2);
    const int cb   = jj << 2;

    const int p0 = __builtin_amdgcn_readfirstlane(rowptr[n]);
    const int p1 = __builtin_amdgcn_readfirstlane(rowptr[n + 1]);

    // pass 1: per-head max (lane jj covers edge p0+jj, strided by 16)
    float mh = -INFINITY;
    for (int b = p0; b < p1; b += 16) {
        const int p = b + jj;
        const int pa = (p < p1) ? p : (p1 - 1);
        float a = alpha4[(long)pa * 4 + h];
        if (p >= p1) a = -INFINITY;
        mh = fmaxf(mh, a);
    }
    mh = fmaxf(mh, __shfl_xor(mh, 1, 64));
    mh = fmaxf(mh, __shfl_xor(mh, 2, 64));
    mh = fmaxf(mh, __shfl_xor(mh, 4, 64));
    mh = fmaxf(mh, __shfl_xor(mh, 8, 64));

    // pass 2: weights + denom + gather-aggregate
    float dsum = 0.f;
    float ac0 = 0.f, ac1 = 0.f, ac2 = 0.f, ac3 = 0.f;
    for (int b = p0; b < p1; b += 16) {
        const int p = b + jj;
        const bool v = (p < p1);
        const int pa = v ? p : (p1 - 1);
        float a = alpha4[(long)pa * 4 + h];
        if (!v) a = -INFINITY;
        const float w = fast_exp(a - mh);          // 0 for invalid lanes
        dsum += w;
        const int sv = srcs[pa];                    // lane jj's edge src
        const int cnt = ((p1 - b) < 16) ? (p1 - b) : 16;
        for (int j = 0; j < cnt; j++) {
            const int sj   = __shfl(sv, j, 64);
            const float wj = __shfl(w, (lane & 48) | j, 64);
            const float4 x4 = *(const float4*)(xl + (long)sj * HC + gc);
            ac0 = fmaf(wj, x4.x, ac0);
            ac1 = fmaf(wj, x4.y, ac1);
            ac2 = fmaf(wj, x4.z, ac2);
            ac3 = fmaf(wj, x4.w, ac3);
        }
    }
    dsum += __shfl_xor(dsum, 1, 64);
    dsum += __shfl_xor(dsum, 2, 64);
    dsum += __shfl_xor(dsum, 4, 64);
    dsum += __shfl_xor(dsum, 8, 64);

    const float inv = 1.0f / (dsum + 1e-16f);
    float v0 = ac0 * inv, v1 = ac1 * inv, v2 = ac2 * inv, v3 = ac3 * inv;

    // head mean across the 4 groups
    v0 += __shfl_xor(v0, 16, 64); v0 += __shfl_xor(v0, 32, 64);
    v1 += __shfl_xor(v1, 16, 64); v1 += __shfl_xor(v1, 32, 64);
    v2 += __shfl_xor(v2, 16, 64); v2 += __shfl_xor(v2, 32, 64);
    v3 += __shfl_xor(v3, 16, 64); v3 += __shfl_xor(v3, 32, 64);

    if (lane < 16) {   // group 0 finishes LN + GELU + store
        const float4 b4 = *(const float4*)(bias + cb);
        v0 = v0 * 0.25f + b4.x;
        v1 = v1 * 0.25f + b4.y;
        v2 = v2 * 0.25f + b4.z;
        v3 = v3 * 0.25f + b4.w;

        float s = (v0 + v1) + (v2 + v3);
        s += __shfl_xor(s, 1, 64); s += __shfl_xor(s, 2, 64);
        s += __shfl_xor(s, 4, 64); s += __shfl_xor(s, 8, 64);
        const float mu = s * (1.0f / 64.0f);
        const float d0 = v0 - mu, d1 = v1 - mu, d2 = v2 - mu, d3 = v3 - mu;
        float q = (d0 * d0 + d1 * d1) + (d2 * d2 + d3 * d3);
        q += __shfl_xor(q, 1, 64); q += __shfl_xor(q, 2, 64);
        q += __shfl_xor(q, 4, 64); q += __shfl_xor(q, 8, 64);
        const float rs = rsqrtf(q * (1.0f / 64.0f) + 1e-5f);

        const float4 g4 = *(const float4*)(lng + cb);
        const float4 c4 = *(const float4*)(lnb + cb);
        float y0 = d0 * rs * g4.x + c4.x;
        float y1 = d1 * rs * g4.y + c4.y;
        float y2 = d2 * rs * g4.z + c4.z;
        float y3 = d3 * rs * g4.w + c4.w;

        if (mode == 0) {
            float4 o;
            o.x = gelu_exact(y0); o.y = gelu_exact(y1);
            o.z = gelu_exact(y2); o.w = gelu_exact(y3);
            *(float4*)(x1out + (long)n * DD + cb) = o;
        } else {
            const float4 id = *(const float4*)(identity + (long)n * DD + cb);
            float4 o;
            o.x = gelu_exact(y0 + id.x); o.y = gelu_exact(y1 + id.y);
            o.z = gelu_exact(y2 + id.z); o.w = gelu_exact(y3 + id.w);
            *(float4*)(outp + (long)n * DD + cb) = o;
        }
    }
}

// ---------- launch ----------
extern "C" void kernel_launch(void* const* d_in, const int* in_sizes, int n_in,
                              void* d_out, int out_size, void* d_ws, size_t ws_size,
                              hipStream_t stream) {
    (void)in_sizes; (void)n_in; (void)out_size; (void)ws_size;

    const float* h     = (const float*)d_in[0];
    const int*   ei    = (const int*)d_in[1];
    const float* ea    = (const float*)d_in[2];
    const float* g1Wl  = (const float*)d_in[3];
    const float* g1bl  = (const float*)d_in[4];
    const float* g1Wr  = (const float*)d_in[5];
    const float* g1br  = (const float*)d_in[6];
    const float* g1We  = (const float*)d_in[7];
    const float* g1att = (const float*)d_in[8];
    const float* g1bias= (const float*)d_in[9];
    const float* ln1g  = (const float*)d_in[10];
    const float* ln1b  = (const float*)d_in[11];
    const float* g2Wl  = (const float*)d_in[12];
    const float* g2bl  = (const float*)d_in[13];
    const float* g2Wr  = (const float*)d_in[14];
    const float* g2br  = (const float*)d_in[15];
    const float* g2We  = (const float*)d_in[16];
    const float* g2att = (const float*)d_in[17];
    const float* g2bias= (const float*)d_in[18];
    const float* ln2g  = (const float*)d_in[19];
    const float* ln2b  = (const float*)d_in[20];

    float* out = (float*)d_out;

    // workspace layout (4-byte units), ~152 MB
    float* ws = (float*)d_ws;
    size_t o = 0;
    float* xl     = ws + o;         o += 12800000;   // N*256
    float* xr     = ws + o;         o += 12800000;   // N*256
    float* x1     = ws + o;         o += 3200000;    // N*64
    int*   rowptr = (int*)(ws + o); o += 50004;      // N+1
    int*   deg    = (int*)(ws + o); o += 50000;
    int*   cursor = (int*)(ws + o); o += 50000;
    int*   bsum   = (int*)(ws + o); o += 256;
    int*   srcs   = (int*)(ws + o); o += 400000;
    int*   dsts   = (int*)(ws + o); o += 400000;
    float* ea_s   = ws + o;         o += 6400000;    // E*16, CSR-sorted
    float* alpha4 = ws + o;         o += 1600000;    // E*4 logits

    const int GEMM_BLOCKS  = (NN + 31) / 32;    // 1563
    const int SCAN_BLOCKS  = (NN + 255) / 256;  // 196
    const int EDGE_BLOCKS  = (EE + 255) / 256;  // 1563
    const int LOGIT_BLOCKS = 2048;              // 8192 waves, ~49 edges each
    const int NODE_BLOCKS  = (NN + 3) / 4;      // 12500

    // ----- CSR build (once; graph identical for both layers) -----
    fill_u32<<<256, 256, 0, stream>>>((unsigned*)deg, 0u, NN);
    hist_k<<<EDGE_BLOCKS, 256, 0, stream>>>(ei, deg);
    scan1_k<<<SCAN_BLOCKS, 256, 0, stream>>>(deg, rowptr, bsum);
    scan2_k<<<1, 256, 0, stream>>>(bsum, SCAN_BLOCKS);
    scan3_k<<<SCAN_BLOCKS, 256, 0, stream>>>(rowptr, bsum, cursor);
    scatter_k<<<EDGE_BLOCKS, 256, 0, stream>>>(ei, cursor, ea, srcs, dsts, ea_s);

    // ----- layer 1 -----
    gemm_node2<<<dim3(GEMM_BLOCKS, 2), 256, 0, stream>>>(h, g1Wl, g1bl, g1Wr, g1br, xl, xr);
    edge_logit_k<<<LOGIT_BLOCKS, 256, 0, stream>>>(srcs, dsts, ea_s, g1We, g1att,
                                                   xl, xr, alpha4);
    node_agg_k<<<NODE_BLOCKS, 256, 0, stream>>>(rowptr, srcs, alpha4, xl,
                                                g1bias, ln1g, ln1b, h, x1, out, 0);

    // ----- layer 2 -----
    gemm_node2<<<dim3(GEMM_BLOCKS, 2), 256, 0, stream>>>(x1, g2Wl, g2bl, g2Wr, g2br, xl, xr);
    edge_logit_k<<<LOGIT_BLOCKS, 256, 0, stream>>>(srcs, dsts, ea_s, g2We, g2att,
                                                   xl, xr, alpha4);
    node_agg_k<<<NODE_BLOCKS, 256, 0, stream>>>(rowptr, srcs, alpha4, xl,
                                                g2bias, ln2g, ln2b, h, x1, out, 1);
}